// Round 14
// baseline (503.150 us; speedup 1.0000x reference)
//
#include <hip/hip_runtime.h>

using u16 = unsigned short;
using u32 = unsigned int;

typedef __bf16 bf16x8 __attribute__((ext_vector_type(8)));
typedef float  f32x4  __attribute__((ext_vector_type(4)));

#define NPOS   225          // 15*15 valid positions
#define ROWP   136          // LDS row stride in ushorts (272B; stride 68 dw -> 2-way-free banks)
#define NROWS  240          // p' = i*16 + j, i<15, j<16 (j==15 rows are zero pads)
#define A_ELEMS (NROWS*ROWP)             // 32640 u16
#define LDS_BYTES (A_ELEMS*2)            // 65280 B < 64 KiB -> NO dynamic-LDS opt-in, 2 blocks/CU
#define RST16 (16*ROWP)                  // one i-row step

// ---- workspace layout ----
// floats [0..768): dconv0 weights [k=c*3+t][s_o] (stored-order o); [768..896): dconv0 bias (stored)
// bf16 (u16) region, offsets in u16 units:
#define WA_PER_L 49152      // per dconv layer: [tap 3][kb 4][ot 8][lane 64][8]
#define WP_OFF   (4*WA_PER_L)          // 196608 ; 6 x [kb 4][ot 8][lane 64][8]
#define WP_PER   16384
#define WF_OFF   (WP_OFF + 6*WP_PER)   // 294912 ; [kb 4][ot 4][lane 64][8]
#define W_U16_TOTAL (WF_OFF + 8192)    // 303104

// storage<->logical channel permutation: swap bits[5:4] and [3:2]; self-inverse
__host__ __device__ __forceinline__ int permc(int c){
  return (c & ~0x3C) | (((c >> 2) & 3) << 4) | (((c >> 4) & 3) << 2);
}

__device__ __forceinline__ float bflo(u32 q){ return __uint_as_float(q << 16); }
__device__ __forceinline__ float bfhi(u32 q){ return __uint_as_float(q & 0xffff0000u); }
__device__ __forceinline__ u16 f2bf(float f){
  u32 u = __float_as_uint(f);
  return (u16)((u + 0x7fffu + ((u >> 16) & 1u)) >> 16);   // RNE (prep kernel only)
}
__device__ __forceinline__ u32 packbf(float a, float b){
  union { __bf16 h[2]; u32 u; } r;
  r.h[0] = (__bf16)a; r.h[1] = (__bf16)b;
  return r.u;
}
__device__ __forceinline__ float silu_f(float x){
  return x * __builtin_amdgcn_rcpf(1.f + __expf(-x));
}
__device__ __forceinline__ f32x4 mfma16(bf16x8 a, bf16x8 b, f32x4 c){
  return __builtin_amdgcn_mfma_f32_16x16x32_bf16(a, b, c, 0, 0, 0);
}
__device__ __forceinline__ uint4 pack_silu2(const f32x4& a, const f32x4& b){
  uint4 q;
  q.x = packbf(silu_f(a[0]), silu_f(a[1]));
  q.y = packbf(silu_f(a[2]), silu_f(a[3]));
  q.z = packbf(silu_f(b[0]), silu_f(b[1]));
  q.w = packbf(silu_f(b[2]), silu_f(b[3]));
  return q;
}
__device__ __forceinline__ uint4 silu_add4(const f32x4& a, const f32x4& b, const uint4& r){
  uint4 q;
  q.x = packbf(silu_f(a[0]) + bflo(r.x), silu_f(a[1]) + bfhi(r.x));
  q.y = packbf(silu_f(a[2]) + bflo(r.y), silu_f(a[3]) + bfhi(r.y));
  q.z = packbf(silu_f(b[0]) + bflo(r.z), silu_f(b[1]) + bfhi(r.z));
  q.w = packbf(silu_f(b[2]) + bflo(r.w), silu_f(b[3]) + bfhi(r.w));
  return q;
}

// ---- weight prep (identical to R12's proven layout) ----
__global__ void prep_w(const float* __restrict__ d0w, const float* __restrict__ d0b,
                       const float* __restrict__ rdw,
                       const float* __restrict__ rpw, const float* __restrict__ c1w,
                       const float* __restrict__ c2w, const float* __restrict__ fw,
                       float* __restrict__ ws)
{
  u16* wsb = (u16*)(ws + 896);
  const int total = 896 + W_U16_TOTAL;
  for (int idx = blockIdx.x*blockDim.x + threadIdx.x; idx < total; idx += gridDim.x*blockDim.x){
    if (idx < 768){                      // dconv0: ws[k*128+s] = w[perm(s)][k]
      int k = idx >> 7, s = idx & 127;
      ws[idx] = d0w[permc(s)*6 + k];
      continue;
    }
    if (idx < 896){
      int s = idx - 768;
      ws[idx] = d0b[permc(s)];
      continue;
    }
    int e = idx - 896;
    float v;
    if (e < WP_OFF){                     // dconv frags [L][tap][kb][ot8][l][j]
      int L = e / WA_PER_L, r = e % WA_PER_L;
      int tap = r / 16384, r1 = r % 16384;
      int kb = r1 >> 12, ot = (r1 >> 9) & 7, l = (r1 >> 3) & 63, j = r1 & 7;
      int o = ot*16 + (l & 15);
      int ks = kb*32 + ((l >> 4) << 3) + j;
      v = rdw[((L*128 + o)*128 + permc(ks))*3 + tap];
    } else if (e < WF_OFF){              // pw frags [i6][kb][ot8][l][j]
      int t2 = e - WP_OFF;
      int i = t2 / WP_PER, r = t2 % WP_PER;
      int kb = r >> 12, ot = (r >> 9) & 7, l = (r >> 3) & 63, j = r & 7;
      int o = ot*16 + (l & 15);
      int ks = kb*32 + ((l >> 4) << 3) + j;
      v = (i < 4) ? rpw[(i*128 + o)*128 + permc(ks)]
        : (i == 4) ? c1w[o*128 + permc(ks)] : c2w[o*128 + permc(ks)];
    } else {                             // final frags [kb][ot4][l][j]
      int e2 = e - WF_OFF;
      int kb = e2 >> 11, ot = (e2 >> 9) & 3, l = (e2 >> 3) & 63, j = e2 & 7;
      int o = ot*16 + (l & 15);
      int ks = kb*32 + ((l >> 4) << 3) + j;
      v = fw[o*128 + permc(ks)];
    }
    wsb[e] = f2bf(v);
  }
}

// ---- dconv 128->128: accumulate all 8 o-tiles for NTL i-rows; no writes ----
// Row-crossing taps (di=+-1) at i==0 / i==14 are skipped (wave-uniform); dj
// shifts land in the zeroed j==15 pad rows automatically.
template<int NTL>
__device__ __forceinline__ void dconv_phase(f32x4 (&acc)[8][2],
    const u16* __restrict__ As, const u16* __restrict__ wd,
    const float* __restrict__ bd, int lane, int T0,
    int dr0, int dr2, int di0, int di2)
{
  const int col = lane & 15, kg = lane >> 4;
  #pragma unroll
  for (int ot=0; ot<8; ++ot){
    f32x4 bz = *(const f32x4*)(bd + ot*16 + kg*4);
    #pragma unroll
    for (int t=0;t<NTL;++t) acc[ot][t] = bz;
  }
  const int rb0 = (T0*16 + col)*ROWP + kg*8;
  #pragma unroll 1
  for (int tap=0; tap<3; ++tap){
    const int di    = (tap==0) ? di0 : (tap==1) ? 0 : di2;
    const int droff = ((tap==0) ? dr0 : (tap==1) ? 0 : dr2)*ROWP;
    #pragma unroll 1
    for (int kb=0; kb<4; ++kb){
      bf16x8 w[8];
      #pragma unroll
      for (int ot=0; ot<8; ++ot)
        w[ot] = *(const bf16x8*)(wd + ((tap*4+kb)*8 + ot)*512 + lane*8);
      #pragma unroll
      for (int t=0; t<NTL; ++t){
        if ((unsigned)(T0 + t + di) < 15u){
          bf16x8 v = *(const bf16x8*)(As + rb0 + t*RST16 + droff + kb*32);
          __builtin_amdgcn_s_setprio(1);
          acc[0][t] = mfma16(w[0], v, acc[0][t]);
          acc[1][t] = mfma16(w[1], v, acc[1][t]);
          acc[2][t] = mfma16(w[2], v, acc[2][t]);
          acc[3][t] = mfma16(w[3], v, acc[3][t]);
          acc[4][t] = mfma16(w[4], v, acc[4][t]);
          acc[5][t] = mfma16(w[5], v, acc[5][t]);
          acc[6][t] = mfma16(w[6], v, acc[6][t]);
          acc[7][t] = mfma16(w[7], v, acc[7][t]);
          __builtin_amdgcn_s_setprio(0);
        }
      }
    }
  }
}

// ---- after barrier: capture residual, write silu(dconv) in place, pw in place + resid ----
template<int NTL>
__device__ __forceinline__ void pwres_phase(f32x4 (&acc)[8][2],
    u16* __restrict__ As, const u16* __restrict__ wpw,
    const float* __restrict__ bp, int lane, int T0)
{
  const int col = lane & 15, kg = lane >> 4;
  const int rb0 = (T0*16 + col)*ROWP;
  uint4 rsd[NTL][4];
  #pragma unroll
  for (int t=0;t<NTL;++t){
    const u16* rp = As + rb0 + t*RST16 + kg*16;
    rsd[t][0] = *(const uint4*)rp;
    rsd[t][1] = *(const uint4*)(rp + 8);
    rsd[t][2] = *(const uint4*)(rp + 64);
    rsd[t][3] = *(const uint4*)(rp + 72);
  }
  #pragma unroll
  for (int t=0;t<NTL;++t){
    if (col < 15){
      u16* dp = As + rb0 + t*RST16 + kg*16;
      *(uint4*)dp      = pack_silu2(acc[0][t], acc[1][t]);
      *(uint4*)(dp+8)  = pack_silu2(acc[2][t], acc[3][t]);
      *(uint4*)(dp+64) = pack_silu2(acc[4][t], acc[5][t]);
      *(uint4*)(dp+72) = pack_silu2(acc[6][t], acc[7][t]);
    }
  }
  #pragma unroll
  for (int t=0;t<NTL;++t){
    f32x4 a[8];
    #pragma unroll
    for (int ot=0;ot<8;++ot) a[ot] = *(const f32x4*)(bp + ot*16 + kg*4);
    const u16* srow = As + rb0 + t*RST16 + kg*8;
    #pragma unroll 1
    for (int kb=0; kb<4; ++kb){
      bf16x8 w[8];
      #pragma unroll
      for (int ot=0; ot<8; ++ot)
        w[ot] = *(const bf16x8*)(wpw + (kb*8 + ot)*512 + lane*8);
      bf16x8 v = *(const bf16x8*)(srow + kb*32);
      __builtin_amdgcn_s_setprio(1);
      a[0] = mfma16(w[0], v, a[0]); a[1] = mfma16(w[1], v, a[1]);
      a[2] = mfma16(w[2], v, a[2]); a[3] = mfma16(w[3], v, a[3]);
      a[4] = mfma16(w[4], v, a[4]); a[5] = mfma16(w[5], v, a[5]);
      a[6] = mfma16(w[6], v, a[6]); a[7] = mfma16(w[7], v, a[7]);
      __builtin_amdgcn_s_setprio(0);
    }
    if (col < 15){
      u16* dp = As + rb0 + t*RST16 + kg*16;
      *(uint4*)dp      = silu_add4(a[0], a[1], rsd[t][0]);
      *(uint4*)(dp+8)  = silu_add4(a[2], a[3], rsd[t][1]);
      *(uint4*)(dp+64) = silu_add4(a[4], a[5], rsd[t][2]);
      *(uint4*)(dp+72) = silu_add4(a[6], a[7], rsd[t][3]);
    }
  }
}

// ---- tail: c1 (no resid), c2 (+resid), final 128->64 to global; same-wave, no barriers ----
template<int NTL>
__device__ __forceinline__ void tail_phase(u16* __restrict__ As,
    const u16* __restrict__ w1, const u16* __restrict__ w2, const u16* __restrict__ wf,
    const float* __restrict__ b1, const float* __restrict__ b2, const float* __restrict__ bf,
    float* __restrict__ out, int lane, int T0, int bd)
{
  const int col = lane & 15, kg = lane >> 4;
  const int rb0 = (T0*16 + col)*ROWP;
  uint4 rsd[NTL][4];
  #pragma unroll
  for (int t=0;t<NTL;++t){
    const u16* rp = As + rb0 + t*RST16 + kg*16;
    rsd[t][0] = *(const uint4*)rp;
    rsd[t][1] = *(const uint4*)(rp + 8);
    rsd[t][2] = *(const uint4*)(rp + 64);
    rsd[t][3] = *(const uint4*)(rp + 72);
  }
  // c1
  #pragma unroll
  for (int t=0;t<NTL;++t){
    f32x4 a[8];
    #pragma unroll
    for (int ot=0;ot<8;++ot) a[ot] = *(const f32x4*)(b1 + ot*16 + kg*4);
    const u16* srow = As + rb0 + t*RST16 + kg*8;
    #pragma unroll 1
    for (int kb=0; kb<4; ++kb){
      bf16x8 w[8];
      #pragma unroll
      for (int ot=0; ot<8; ++ot)
        w[ot] = *(const bf16x8*)(w1 + (kb*8 + ot)*512 + lane*8);
      bf16x8 v = *(const bf16x8*)(srow + kb*32);
      __builtin_amdgcn_s_setprio(1);
      a[0] = mfma16(w[0], v, a[0]); a[1] = mfma16(w[1], v, a[1]);
      a[2] = mfma16(w[2], v, a[2]); a[3] = mfma16(w[3], v, a[3]);
      a[4] = mfma16(w[4], v, a[4]); a[5] = mfma16(w[5], v, a[5]);
      a[6] = mfma16(w[6], v, a[6]); a[7] = mfma16(w[7], v, a[7]);
      __builtin_amdgcn_s_setprio(0);
    }
    if (col < 15){
      u16* dp = As + rb0 + t*RST16 + kg*16;
      *(uint4*)dp      = pack_silu2(a[0], a[1]);
      *(uint4*)(dp+8)  = pack_silu2(a[2], a[3]);
      *(uint4*)(dp+64) = pack_silu2(a[4], a[5]);
      *(uint4*)(dp+72) = pack_silu2(a[6], a[7]);
    }
  }
  // c2 + resid
  #pragma unroll
  for (int t=0;t<NTL;++t){
    f32x4 a[8];
    #pragma unroll
    for (int ot=0;ot<8;++ot) a[ot] = *(const f32x4*)(b2 + ot*16 + kg*4);
    const u16* srow = As + rb0 + t*RST16 + kg*8;
    #pragma unroll 1
    for (int kb=0; kb<4; ++kb){
      bf16x8 w[8];
      #pragma unroll
      for (int ot=0; ot<8; ++ot)
        w[ot] = *(const bf16x8*)(w2 + (kb*8 + ot)*512 + lane*8);
      bf16x8 v = *(const bf16x8*)(srow + kb*32);
      __builtin_amdgcn_s_setprio(1);
      a[0] = mfma16(w[0], v, a[0]); a[1] = mfma16(w[1], v, a[1]);
      a[2] = mfma16(w[2], v, a[2]); a[3] = mfma16(w[3], v, a[3]);
      a[4] = mfma16(w[4], v, a[4]); a[5] = mfma16(w[5], v, a[5]);
      a[6] = mfma16(w[6], v, a[6]); a[7] = mfma16(w[7], v, a[7]);
      __builtin_amdgcn_s_setprio(0);
    }
    if (col < 15){
      u16* dp = As + rb0 + t*RST16 + kg*16;
      *(uint4*)dp      = silu_add4(a[0], a[1], rsd[t][0]);
      *(uint4*)(dp+8)  = silu_add4(a[2], a[3], rsd[t][1]);
      *(uint4*)(dp+64) = silu_add4(a[4], a[5], rsd[t][2]);
      *(uint4*)(dp+72) = silu_add4(a[6], a[7], rsd[t][3]);
    }
  }
  // final
  #pragma unroll
  for (int t=0;t<NTL;++t){
    f32x4 a4[4];
    #pragma unroll
    for (int ot=0;ot<4;++ot) a4[ot] = *(const f32x4*)(bf + ot*16 + kg*4);
    const u16* srow = As + rb0 + t*RST16 + kg*8;
    #pragma unroll 1
    for (int kb=0; kb<4; ++kb){
      bf16x8 w[4];
      #pragma unroll
      for (int ot=0; ot<4; ++ot)
        w[ot] = *(const bf16x8*)(wf + (kb*4 + ot)*512 + lane*8);
      bf16x8 v = *(const bf16x8*)(srow + kb*32);
      __builtin_amdgcn_s_setprio(1);
      a4[0] = mfma16(w[0], v, a4[0]); a4[1] = mfma16(w[1], v, a4[1]);
      a4[2] = mfma16(w[2], v, a4[2]); a4[3] = mfma16(w[3], v, a4[3]);
      __builtin_amdgcn_s_setprio(0);
    }
    if (col < 15){
      #pragma unroll
      for (int ot=0; ot<4; ++ot){
        float* op = out + ((size_t)(bd*64 + ot*16 + kg*4))*NPOS + (T0+t)*15 + col;
        op[0]      = a4[ot][0];
        op[NPOS]   = a4[ot][1];
        op[2*NPOS] = a4[ot][2];
        op[3*NPOS] = a4[ot][3];
      }
    }
  }
}

__global__ void __launch_bounds__(512, 4)   // 8 waves/block, 2 blocks/CU -> 4 waves/EU, 128-VGPR cap
mix9_main(const float* __restrict__ x,
          const float* __restrict__ b_rd,
          const float* __restrict__ b_rp,
          const float* __restrict__ b_c1,
          const float* __restrict__ b_c2,
          const float* __restrict__ b_fin,
          const float* __restrict__ wt,
          float* __restrict__ out)
{
  extern __shared__ u16 sm[];
  u16* As = sm;              // [240][136] p'-rows (stored-perm ch), j==15 pad rows zero

  const int blk  = blockIdx.x;
  const int b    = blk >> 2, d = blk & 3;
  const int tid  = threadIdx.x;
  const int wave = __builtin_amdgcn_readfirstlane(tid >> 6);
  const int lane = tid & 63;
  const int T0   = 2*wave;            // wave 7 -> T0=14, NTL=1

  const int DI0[4] = {0,-1, 1,-1}, DJ0[4] = {-1, 0,-1,-1};
  const int DI2[4] = {0, 1,-1, 1}, DJ2[4] = { 1, 0, 1, 1};
  const int di0 = DI0[d], dj0 = DJ0[d], di2 = DI2[d], dj2 = DJ2[d];
  const int dr0 = di0*16 + dj0;
  const int dr2 = di2*16 + dj2;

  // zero the whole buffer (incl. j==15 pad rows, which must STAY zero)
  for (int k2 = tid; k2 < A_ELEMS; k2 += 512) As[k2] = 0;
  __syncthreads();

  // ---- dconv0: 2 -> 128, x read directly from global (L2-resident) ----
  {
    const float* b0p = wt + 768;
    const int ob = wave * 16;
    const float* xb = x + b*450;
    #pragma unroll 1
    for (int pb = 0; pb < 4; ++pb){
      int pp = pb*64 + lane;              // p' = i*16 + j
      int i = pp >> 4, j = pp & 15;
      if (i >= 15 || j >= 15) continue;
      float acc0[16];
      #pragma unroll
      for (int oo=0;oo<16;++oo) acc0[oo] = b0p[ob+oo];
      int i0=i+di0, j0=j+dj0, i2=i+di2, j2=j+dj2;
      bool v0 = ((unsigned)i0<15u) && ((unsigned)j0<15u);
      bool v2 = ((unsigned)i2<15u) && ((unsigned)j2<15u);
      #pragma unroll
      for (int c=0;c<2;++c){
        float x0 = v0 ? xb[c*NPOS + i0*15 + j0] : 0.f;
        float x1 = xb[c*NPOS + i*15 + j];
        float x2 = v2 ? xb[c*NPOS + i2*15 + j2] : 0.f;
        const float* w0r = wt + (c*3+0)*128 + ob;
        const float* w1r = wt + (c*3+1)*128 + ob;
        const float* w2r = wt + (c*3+2)*128 + ob;
        #pragma unroll
        for (int oo=0;oo<16;++oo)
          acc0[oo] = fmaf(w0r[oo],x0, fmaf(w1r[oo],x1, fmaf(w2r[oo],x2, acc0[oo])));
      }
      u16* dp = As + pp*ROWP + ob;
      #pragma unroll
      for (int oo=0;oo<16;oo+=2)
        *(u32*)(dp+oo) = packbf(silu_f(acc0[oo]), silu_f(acc0[oo+1]));
    }
  }
  __syncthreads();

  const u16* wsb = (const u16*)(wt + 896);
  f32x4 acc[8][2];

  // ---- 4 directional res blocks: dconv -> BARRIER -> in-place write + pw ----
  #pragma unroll 1
  for (int L = 0; L < 4; ++L){
    if (wave < 7) dconv_phase<2>(acc, As, wsb + L*WA_PER_L, b_rd + L*128, lane, T0, dr0, dr2, di0, di2);
    else          dconv_phase<1>(acc, As, wsb + L*WA_PER_L, b_rd + L*128, lane, 14, dr0, dr2, di0, di2);
    __syncthreads();
    if (wave < 7) pwres_phase<2>(acc, As, wsb + WP_OFF + L*WP_PER, b_rp + L*128, lane, T0);
    else          pwres_phase<1>(acc, As, wsb + WP_OFF + L*WP_PER, b_rp + L*128, lane, 14);
    if (L < 3) __syncthreads();
  }

  // ---- Conv0d res block + final (own rows only; no barriers) ----
  if (wave < 7)
    tail_phase<2>(As, wsb + WP_OFF + 4*WP_PER, wsb + WP_OFF + 5*WP_PER, wsb + WF_OFF,
                  b_c1, b_c2, b_fin, out, lane, T0, b*4 + d);
  else
    tail_phase<1>(As, wsb + WP_OFF + 4*WP_PER, wsb + WP_OFF + 5*WP_PER, wsb + WF_OFF,
                  b_c1, b_c2, b_fin, out, lane, 14, b*4 + d);
}

extern "C" void kernel_launch(void* const* d_in, const int* in_sizes, int n_in,
                              void* d_out, int out_size, void* d_ws, size_t ws_size,
                              hipStream_t stream)
{
  const float* x     = (const float*)d_in[0];
  const float* w_d0  = (const float*)d_in[1];
  const float* b_d0  = (const float*)d_in[2];
  const float* w_rd  = (const float*)d_in[3];
  const float* b_rd  = (const float*)d_in[4];
  const float* w_rp  = (const float*)d_in[5];
  const float* b_rp  = (const float*)d_in[6];
  const float* w_c1  = (const float*)d_in[7];
  const float* b_c1  = (const float*)d_in[8];
  const float* w_c2  = (const float*)d_in[9];
  const float* b_c2  = (const float*)d_in[10];
  const float* w_fin = (const float*)d_in[11];
  const float* b_fin = (const float*)d_in[12];
  float* wt  = (float*)d_ws;
  float* out = (float*)d_out;

  prep_w<<<128, 512, 0, stream>>>(w_d0, b_d0, w_rd, w_rp, w_c1, w_c2, w_fin, wt);

  // LDS_BYTES = 65280 < 64 KiB default limit: no hipFuncSetAttribute opt-in needed.
  mix9_main<<<1024, 512, LDS_BYTES, stream>>>(x, b_rd, b_rp, b_c1, b_c2, b_fin, wt, out);
}

// Round 15
// 300.189 us; speedup vs baseline: 1.6761x; 1.6761x over previous
//
#include <hip/hip_runtime.h>

using u16 = unsigned short;
using u32 = unsigned int;

typedef __bf16 bf16x8 __attribute__((ext_vector_type(8)));
typedef float  f32x4  __attribute__((ext_vector_type(4)));

#define NPOS   225          // 15*15 valid positions
#define ROWP   136          // LDS row stride in ushorts (272B)
#define NROWS  240          // p' = i*16 + j, i<15, j<16 (j==15 rows zero pads)
#define A_ELEMS (NROWS*ROWP)             // 32640 u16
#define LDS_BYTES (A_ELEMS*2)            // 65280 B < 64 KiB -> 2 blocks/CU if VGPR<=128
#define RST16 (16*ROWP)                  // one i-row step

// ---- workspace layout ----
// floats [0..768): dconv0 weights [k=c*3+t][s_o]; [768..896): dconv0 bias (stored-perm)
// bf16 (u16) region, offsets in u16 units:
#define WA_PER_L 49152      // per dconv layer: [tap 3][kb 4][ot 8][lane 64][8]
#define WP_OFF   (4*WA_PER_L)          // 196608 ; 6 x [kb 4][ot 8][lane 64][8]
#define WP_PER   16384
#define WF_OFF   (WP_OFF + 6*WP_PER)   // 294912 ; [kb 4][ot 4][lane 64][8]
#define W_U16_TOTAL (WF_OFF + 8192)    // 303104

// storage<->logical channel permutation: swap bits[5:4] and [3:2]; self-inverse
__host__ __device__ __forceinline__ int permc(int c){
  return (c & ~0x3C) | (((c >> 2) & 3) << 4) | (((c >> 4) & 3) << 2);
}

__device__ __forceinline__ float bflo(u32 q){ return __uint_as_float(q << 16); }
__device__ __forceinline__ float bfhi(u32 q){ return __uint_as_float(q & 0xffff0000u); }
__device__ __forceinline__ u16 f2bf(float f){
  u32 u = __float_as_uint(f);
  return (u16)((u + 0x7fffu + ((u >> 16) & 1u)) >> 16);   // RNE (prep kernel only)
}
__device__ __forceinline__ u32 packbf(float a, float b){
  union { __bf16 h[2]; u32 u; } r;
  r.h[0] = (__bf16)a; r.h[1] = (__bf16)b;
  return r.u;
}
__device__ __forceinline__ float silu_f(float x){
  return x * __builtin_amdgcn_rcpf(1.f + __expf(-x));
}
__device__ __forceinline__ f32x4 mfma16(bf16x8 a, bf16x8 b, f32x4 c){
  return __builtin_amdgcn_mfma_f32_16x16x32_bf16(a, b, c, 0, 0, 0);
}
__device__ __forceinline__ uint4 pack_silu2(const f32x4& a, const f32x4& b){
  uint4 q;
  q.x = packbf(silu_f(a[0]), silu_f(a[1]));
  q.y = packbf(silu_f(a[2]), silu_f(a[3]));
  q.z = packbf(silu_f(b[0]), silu_f(b[1]));
  q.w = packbf(silu_f(b[2]), silu_f(b[3]));
  return q;
}
__device__ __forceinline__ uint4 silu_add4(const f32x4& a, const f32x4& b, const uint4& r){
  uint4 q;
  q.x = packbf(silu_f(a[0]) + bflo(r.x), silu_f(a[1]) + bfhi(r.x));
  q.y = packbf(silu_f(a[2]) + bflo(r.y), silu_f(a[3]) + bfhi(r.y));
  q.z = packbf(silu_f(b[0]) + bflo(r.z), silu_f(b[1]) + bfhi(r.z));
  q.w = packbf(silu_f(b[2]) + bflo(r.w), silu_f(b[3]) + bfhi(r.w));
  return q;
}

// ---- weight prep (identical to R12/R14 proven layout) ----
__global__ void prep_w(const float* __restrict__ d0w, const float* __restrict__ d0b,
                       const float* __restrict__ rdw,
                       const float* __restrict__ rpw, const float* __restrict__ c1w,
                       const float* __restrict__ c2w, const float* __restrict__ fw,
                       float* __restrict__ ws)
{
  u16* wsb = (u16*)(ws + 896);
  const int total = 896 + W_U16_TOTAL;
  for (int idx = blockIdx.x*blockDim.x + threadIdx.x; idx < total; idx += gridDim.x*blockDim.x){
    if (idx < 768){
      int k = idx >> 7, s = idx & 127;
      ws[idx] = d0w[permc(s)*6 + k];
      continue;
    }
    if (idx < 896){
      int s = idx - 768;
      ws[idx] = d0b[permc(s)];
      continue;
    }
    int e = idx - 896;
    float v;
    if (e < WP_OFF){                     // dconv frags [L][tap][kb][ot8][l][j]
      int L = e / WA_PER_L, r = e % WA_PER_L;
      int tap = r / 16384, r1 = r % 16384;
      int kb = r1 >> 12, ot = (r1 >> 9) & 7, l = (r1 >> 3) & 63, j = r1 & 7;
      int o = ot*16 + (l & 15);
      int ks = kb*32 + ((l >> 4) << 3) + j;
      v = rdw[((L*128 + o)*128 + permc(ks))*3 + tap];
    } else if (e < WF_OFF){              // pw frags [i6][kb][ot8][l][j]
      int t2 = e - WP_OFF;
      int i = t2 / WP_PER, r = t2 % WP_PER;
      int kb = r >> 12, ot = (r >> 9) & 7, l = (r >> 3) & 63, j = r & 7;
      int o = ot*16 + (l & 15);
      int ks = kb*32 + ((l >> 4) << 3) + j;
      v = (i < 4) ? rpw[(i*128 + o)*128 + permc(ks)]
        : (i == 4) ? c1w[o*128 + permc(ks)] : c2w[o*128 + permc(ks)];
    } else {                             // final frags [kb][ot4][l][j]
      int e2 = e - WF_OFF;
      int kb = e2 >> 11, ot = (e2 >> 9) & 3, l = (e2 >> 3) & 63, j = e2 & 7;
      int o = ot*16 + (l & 15);
      int ks = kb*32 + ((l >> 4) << 3) + j;
      v = fw[o*128 + permc(ks)];
    }
    wsb[e] = f2bf(v);
  }
}

// ---- dconv 128->128: o-half split; results pre-packed to bf16 in pk[NTL][4] ----
template<int NTL>
__device__ __forceinline__ void dconv_phase(uint4 (&pk)[NTL][4],
    const u16* __restrict__ As, const u16* __restrict__ wd,
    const float* __restrict__ bd, int lane, int T0,
    int dr0, int dr2, int di0, int di2)
{
  const int col = lane & 15, kg = lane >> 4;
  const int rb0 = (T0*16 + col)*ROWP + kg*8;
  #pragma unroll
  for (int oh=0; oh<2; ++oh){
    f32x4 acc[4][NTL];
    #pragma unroll
    for (int ot=0; ot<4; ++ot){
      f32x4 bz = *(const f32x4*)(bd + (oh*4+ot)*16 + kg*4);
      #pragma unroll
      for (int t=0;t<NTL;++t) acc[ot][t] = bz;
    }
    #pragma unroll 1
    for (int tap=0; tap<3; ++tap){
      const int di    = (tap==0) ? di0 : (tap==1) ? 0 : di2;
      const int droff = ((tap==0) ? dr0 : (tap==1) ? 0 : dr2)*ROWP;
      #pragma unroll 1
      for (int kb=0; kb<4; ++kb){
        bf16x8 w[4];
        #pragma unroll
        for (int ot=0; ot<4; ++ot)
          w[ot] = *(const bf16x8*)(wd + ((tap*4+kb)*8 + oh*4 + ot)*512 + lane*8);
        #pragma unroll
        for (int t=0; t<NTL; ++t){
          if ((unsigned)(T0 + t + di) < 15u){
            bf16x8 v = *(const bf16x8*)(As + rb0 + t*RST16 + droff + kb*32);
            __builtin_amdgcn_s_setprio(1);
            acc[0][t] = mfma16(w[0], v, acc[0][t]);
            acc[1][t] = mfma16(w[1], v, acc[1][t]);
            acc[2][t] = mfma16(w[2], v, acc[2][t]);
            acc[3][t] = mfma16(w[3], v, acc[3][t]);
            __builtin_amdgcn_s_setprio(0);
          }
        }
      }
    }
    #pragma unroll
    for (int t=0;t<NTL;++t){
      pk[t][oh*2]   = pack_silu2(acc[0][t], acc[1][t]);
      pk[t][oh*2+1] = pack_silu2(acc[2][t], acc[3][t]);
    }
  }
}

// ---- after barrier: per tile {capture resid, write dconv-out, pw, write pw+resid} ----
template<int NTL>
__device__ __forceinline__ void pwres_phase(uint4 (&pk)[NTL][4],
    u16* __restrict__ As, const u16* __restrict__ wpw,
    const float* __restrict__ bp, int lane, int T0)
{
  const int col = lane & 15, kg = lane >> 4;
  const int rb0 = (T0*16 + col)*ROWP;
  #pragma unroll
  for (int t=0;t<NTL;++t){
    u16* rowp = As + rb0 + t*RST16;
    const u16* rp = rowp + kg*16;
    uint4 rsd[4];
    rsd[0] = *(const uint4*)rp;
    rsd[1] = *(const uint4*)(rp + 8);
    rsd[2] = *(const uint4*)(rp + 64);
    rsd[3] = *(const uint4*)(rp + 72);
    if (col < 15){
      u16* dp = rowp + kg*16;
      *(uint4*)dp      = pk[t][0];
      *(uint4*)(dp+8)  = pk[t][1];
      *(uint4*)(dp+64) = pk[t][2];
      *(uint4*)(dp+72) = pk[t][3];
    }
    const u16* srow = rowp + kg*8;
    uint4 pout[4];
    #pragma unroll
    for (int oh=0; oh<2; ++oh){
      f32x4 a[4];
      #pragma unroll
      for (int ot=0;ot<4;++ot) a[ot] = *(const f32x4*)(bp + (oh*4+ot)*16 + kg*4);
      #pragma unroll 1
      for (int kb=0; kb<4; ++kb){
        bf16x8 w[4];
        #pragma unroll
        for (int ot=0; ot<4; ++ot)
          w[ot] = *(const bf16x8*)(wpw + (kb*8 + oh*4 + ot)*512 + lane*8);
        bf16x8 v = *(const bf16x8*)(srow + kb*32);
        __builtin_amdgcn_s_setprio(1);
        a[0] = mfma16(w[0], v, a[0]); a[1] = mfma16(w[1], v, a[1]);
        a[2] = mfma16(w[2], v, a[2]); a[3] = mfma16(w[3], v, a[3]);
        __builtin_amdgcn_s_setprio(0);
      }
      pout[oh*2]   = silu_add4(a[0], a[1], rsd[oh*2]);
      pout[oh*2+1] = silu_add4(a[2], a[3], rsd[oh*2+1]);
    }
    if (col < 15){
      u16* dp = rowp + kg*16;
      *(uint4*)dp      = pout[0];
      *(uint4*)(dp+8)  = pout[1];
      *(uint4*)(dp+64) = pout[2];
      *(uint4*)(dp+72) = pout[3];
    }
  }
}

// ---- tail: per tile {capture resid, c1, c2+resid, final->global}; no barriers ----
template<int NTL>
__device__ __forceinline__ void tail_phase(u16* __restrict__ As,
    const u16* __restrict__ w1, const u16* __restrict__ w2, const u16* __restrict__ wf,
    const float* __restrict__ b1, const float* __restrict__ b2, const float* __restrict__ bf,
    float* __restrict__ out, int lane, int T0, int bd)
{
  const int col = lane & 15, kg = lane >> 4;
  const int rb0 = (T0*16 + col)*ROWP;
  #pragma unroll
  for (int t=0;t<NTL;++t){
    u16* rowp = As + rb0 + t*RST16;
    const u16* rp = rowp + kg*16;
    uint4 rsd[4];
    rsd[0] = *(const uint4*)rp;
    rsd[1] = *(const uint4*)(rp + 8);
    rsd[2] = *(const uint4*)(rp + 64);
    rsd[3] = *(const uint4*)(rp + 72);
    const u16* srow = rowp + kg*8;
    // c1 (reads pre-c1 value; buffer writes deferred via pout)
    {
      uint4 pout[4];
      #pragma unroll
      for (int oh=0; oh<2; ++oh){
        f32x4 a[4];
        #pragma unroll
        for (int ot=0;ot<4;++ot) a[ot] = *(const f32x4*)(b1 + (oh*4+ot)*16 + kg*4);
        #pragma unroll 1
        for (int kb=0; kb<4; ++kb){
          bf16x8 w[4];
          #pragma unroll
          for (int ot=0; ot<4; ++ot)
            w[ot] = *(const bf16x8*)(w1 + (kb*8 + oh*4 + ot)*512 + lane*8);
          bf16x8 v = *(const bf16x8*)(srow + kb*32);
          __builtin_amdgcn_s_setprio(1);
          a[0] = mfma16(w[0], v, a[0]); a[1] = mfma16(w[1], v, a[1]);
          a[2] = mfma16(w[2], v, a[2]); a[3] = mfma16(w[3], v, a[3]);
          __builtin_amdgcn_s_setprio(0);
        }
        pout[oh*2]   = pack_silu2(a[0], a[1]);
        pout[oh*2+1] = pack_silu2(a[2], a[3]);
      }
      if (col < 15){
        u16* dp = rowp + kg*16;
        *(uint4*)dp      = pout[0];
        *(uint4*)(dp+8)  = pout[1];
        *(uint4*)(dp+64) = pout[2];
        *(uint4*)(dp+72) = pout[3];
      }
    }
    // c2 + resid
    {
      uint4 pout[4];
      #pragma unroll
      for (int oh=0; oh<2; ++oh){
        f32x4 a[4];
        #pragma unroll
        for (int ot=0;ot<4;++ot) a[ot] = *(const f32x4*)(b2 + (oh*4+ot)*16 + kg*4);
        #pragma unroll 1
        for (int kb=0; kb<4; ++kb){
          bf16x8 w[4];
          #pragma unroll
          for (int ot=0; ot<4; ++ot)
            w[ot] = *(const bf16x8*)(w2 + (kb*8 + oh*4 + ot)*512 + lane*8);
          bf16x8 v = *(const bf16x8*)(srow + kb*32);
          __builtin_amdgcn_s_setprio(1);
          a[0] = mfma16(w[0], v, a[0]); a[1] = mfma16(w[1], v, a[1]);
          a[2] = mfma16(w[2], v, a[2]); a[3] = mfma16(w[3], v, a[3]);
          __builtin_amdgcn_s_setprio(0);
        }
        pout[oh*2]   = silu_add4(a[0], a[1], rsd[oh*2]);
        pout[oh*2+1] = silu_add4(a[2], a[3], rsd[oh*2+1]);
      }
      if (col < 15){
        u16* dp = rowp + kg*16;
        *(uint4*)dp      = pout[0];
        *(uint4*)(dp+8)  = pout[1];
        *(uint4*)(dp+64) = pout[2];
        *(uint4*)(dp+72) = pout[3];
      }
    }
    // final 128->64
    {
      f32x4 a4[4];
      #pragma unroll
      for (int ot=0;ot<4;++ot) a4[ot] = *(const f32x4*)(bf + ot*16 + kg*4);
      #pragma unroll 1
      for (int kb=0; kb<4; ++kb){
        bf16x8 w[4];
        #pragma unroll
        for (int ot=0; ot<4; ++ot)
          w[ot] = *(const bf16x8*)(wf + (kb*4 + ot)*512 + lane*8);
        bf16x8 v = *(const bf16x8*)(srow + kb*32);
        __builtin_amdgcn_s_setprio(1);
        a4[0] = mfma16(w[0], v, a4[0]); a4[1] = mfma16(w[1], v, a4[1]);
        a4[2] = mfma16(w[2], v, a4[2]); a4[3] = mfma16(w[3], v, a4[3]);
        __builtin_amdgcn_s_setprio(0);
      }
      if (col < 15){
        #pragma unroll
        for (int ot=0; ot<4; ++ot){
          float* op = out + ((size_t)(bd*64 + ot*16 + kg*4))*NPOS + (T0+t)*15 + col;
          op[0]      = a4[ot][0];
          op[NPOS]   = a4[ot][1];
          op[2*NPOS] = a4[ot][2];
          op[3*NPOS] = a4[ot][3];
        }
      }
    }
  }
}

__global__ void __launch_bounds__(512, 2)
mix9_main(const float* __restrict__ x,
          const float* __restrict__ b_rd,
          const float* __restrict__ b_rp,
          const float* __restrict__ b_c1,
          const float* __restrict__ b_c2,
          const float* __restrict__ b_fin,
          const float* __restrict__ wt,
          float* __restrict__ out)
{
  extern __shared__ u16 sm[];
  u16* As = sm;              // [240][136] p'-rows (stored-perm ch), j==15 pad rows zero

  const int blk  = blockIdx.x;
  const int b    = blk >> 2, d = blk & 3;
  const int tid  = threadIdx.x;
  const int wave = __builtin_amdgcn_readfirstlane(tid >> 6);
  const int lane = tid & 63;
  const int T0   = 2*wave;            // wave 7 -> T0=14, NTL=1

  const int DI0[4] = {0,-1, 1,-1}, DJ0[4] = {-1, 0,-1,-1};
  const int DI2[4] = {0, 1,-1, 1}, DJ2[4] = { 1, 0, 1, 1};
  const int di0 = DI0[d], dj0 = DJ0[d], di2 = DI2[d], dj2 = DJ2[d];
  const int dr0 = di0*16 + dj0;
  const int dr2 = di2*16 + dj2;

  // zero the whole buffer (incl. j==15 pad rows, which must STAY zero)
  for (int k2 = tid; k2 < A_ELEMS; k2 += 512) As[k2] = 0;
  __syncthreads();

  // ---- dconv0: 2 -> 128, x read directly from global (L2-resident) ----
  {
    const float* b0p = wt + 768;
    const int ob = wave * 16;
    const float* xb = x + b*450;
    #pragma unroll 1
    for (int pb = 0; pb < 4; ++pb){
      int pp = pb*64 + lane;              // p' = i*16 + j
      int i = pp >> 4, j = pp & 15;
      if (i >= 15 || j >= 15) continue;
      float acc0[16];
      #pragma unroll
      for (int oo=0;oo<16;++oo) acc0[oo] = b0p[ob+oo];
      int i0=i+di0, j0=j+dj0, i2=i+di2, j2=j+dj2;
      bool v0 = ((unsigned)i0<15u) && ((unsigned)j0<15u);
      bool v2 = ((unsigned)i2<15u) && ((unsigned)j2<15u);
      #pragma unroll
      for (int c=0;c<2;++c){
        float x0 = v0 ? xb[c*NPOS + i0*15 + j0] : 0.f;
        float x1 = xb[c*NPOS + i*15 + j];
        float x2 = v2 ? xb[c*NPOS + i2*15 + j2] : 0.f;
        const float* w0r = wt + (c*3+0)*128 + ob;
        const float* w1r = wt + (c*3+1)*128 + ob;
        const float* w2r = wt + (c*3+2)*128 + ob;
        #pragma unroll
        for (int oo=0;oo<16;++oo)
          acc0[oo] = fmaf(w0r[oo],x0, fmaf(w1r[oo],x1, fmaf(w2r[oo],x2, acc0[oo])));
      }
      u16* dp = As + pp*ROWP + ob;
      #pragma unroll
      for (int oo=0;oo<16;oo+=2)
        *(u32*)(dp+oo) = packbf(silu_f(acc0[oo]), silu_f(acc0[oo+1]));
    }
  }
  __syncthreads();

  const u16* wsb = (const u16*)(wt + 896);

  // ---- 4 directional res blocks: dconv -> BARRIER -> in-place write + pw ----
  #pragma unroll 1
  for (int L = 0; L < 4; ++L){
    if (wave < 7){
      uint4 pk[2][4];
      dconv_phase<2>(pk, As, wsb + L*WA_PER_L, b_rd + L*128, lane, T0, dr0, dr2, di0, di2);
      __syncthreads();
      pwres_phase<2>(pk, As, wsb + WP_OFF + L*WP_PER, b_rp + L*128, lane, T0);
    } else {
      uint4 pk[1][4];
      dconv_phase<1>(pk, As, wsb + L*WA_PER_L, b_rd + L*128, lane, 14, dr0, dr2, di0, di2);
      __syncthreads();
      pwres_phase<1>(pk, As, wsb + WP_OFF + L*WP_PER, b_rp + L*128, lane, 14);
    }
    if (L < 3) __syncthreads();
  }

  // ---- Conv0d res block + final (own rows only; no barriers) ----
  if (wave < 7)
    tail_phase<2>(As, wsb + WP_OFF + 4*WP_PER, wsb + WP_OFF + 5*WP_PER, wsb + WF_OFF,
                  b_c1, b_c2, b_fin, out, lane, T0, b*4 + d);
  else
    tail_phase<1>(As, wsb + WP_OFF + 4*WP_PER, wsb + WP_OFF + 5*WP_PER, wsb + WF_OFF,
                  b_c1, b_c2, b_fin, out, lane, 14, b*4 + d);
}

extern "C" void kernel_launch(void* const* d_in, const int* in_sizes, int n_in,
                              void* d_out, int out_size, void* d_ws, size_t ws_size,
                              hipStream_t stream)
{
  const float* x     = (const float*)d_in[0];
  const float* w_d0  = (const float*)d_in[1];
  const float* b_d0  = (const float*)d_in[2];
  const float* w_rd  = (const float*)d_in[3];
  const float* b_rd  = (const float*)d_in[4];
  const float* w_rp  = (const float*)d_in[5];
  const float* b_rp  = (const float*)d_in[6];
  const float* w_c1  = (const float*)d_in[7];
  const float* b_c1  = (const float*)d_in[8];
  const float* w_c2  = (const float*)d_in[9];
  const float* b_c2  = (const float*)d_in[10];
  const float* w_fin = (const float*)d_in[11];
  const float* b_fin = (const float*)d_in[12];
  float* wt  = (float*)d_ws;
  float* out = (float*)d_out;

  prep_w<<<128, 512, 0, stream>>>(w_d0, b_d0, w_rd, w_rp, w_c1, w_c2, w_fin, wt);

  // LDS_BYTES = 65280 < 64 KiB: no dynamic-LDS opt-in; 2 blocks/CU if VGPR <= 128.
  mix9_main<<<1024, 512, LDS_BYTES, stream>>>(x, b_rd, b_rp, b_c1, b_c2, b_fin, wt, out);
}